// Round 17
// baseline (339.683 us; speedup 1.0000x reference)
//
#include <hip/hip_runtime.h>

// Qwen3 MoE experts: per-expert SwiGLU MLP.
//   gate = rin @ gate_proj^T ; up = rin @ up_proj^T
//   hidden = silu(gate) * up ; out = hidden @ down_proj^T
// E=32, T=512, H=2048, I=768. f32 inputs; bf16 MFMA, f32 accum.
//
// R17: gateup = R13/R16 verbatim (245us, confirmed twice).
//      down rebuilt on the same reg-staged bf16 structure: B converted to
//      bf16 AT STAGE TIME -> LDS traffic 72->48 KB/iter (down is measured
//      LDS-throughput-bound: 72KB*8slots*24iter/85B/cyc = 69us = its dur),
//      and LDS 48->32 KB -> 3 blocks/CU (the session's one monotone lever).
// ws: hidden [E,T,I] bf16 = 24 MB.

#define NE 32
#define NT 512
#define NH 2048
#define NI 768

typedef short        short8  __attribute__((ext_vector_type(8)));
typedef float        floatx4 __attribute__((ext_vector_type(4)));
typedef unsigned int uintx4  __attribute__((ext_vector_type(4)));

__device__ __forceinline__ unsigned int cvt_pk_bf16(float lo, float hi) {
    unsigned int r;
    asm("v_cvt_pk_bf16_f32 %0, %1, %2" : "=v"(r) : "v"(lo), "v"(hi));
    return r;
}

__device__ __forceinline__ uintx4 pack8(floatx4 x0, floatx4 x1) {
    uintx4 u;
    u[0] = cvt_pk_bf16(x0[0], x0[1]);
    u[1] = cvt_pk_bf16(x0[2], x0[3]);
    u[2] = cvt_pk_bf16(x1[0], x1[1]);
    u[3] = cvt_pk_bf16(x1[2], x1[3]);
    return u;
}

__device__ __forceinline__ ushort f2bf(float f) {
    union { float f; unsigned int u; } v; v.f = f;
    unsigned int r = v.u + 0x7fffu + ((v.u >> 16) & 1u);
    return (ushort)(r >> 16);
}

// ---------------------------------------------------------------------------
// Kernel 1: fused gate+up + SwiGLU -> hidden(bf16).  [R13/R16 verbatim]
// BM=128(T) x BN=64(I), BK=32 over H. 256 thr = 4 waves (2x2), per GEMM
// 4x2 frags of 16x16 -> acc 64 AGPR. LDS 32 KB -> 3 blocks/CU.
// ---------------------------------------------------------------------------
__global__ __launch_bounds__(256, 3) void moe_gateup(
    const float* __restrict__ rin, const float* __restrict__ gate,
    const float* __restrict__ up, ushort* __restrict__ hidden)
{
    __shared__ ushort SA[2][128][32];
    __shared__ ushort SG[2][64][32];
    __shared__ ushort SU[2][64][32];

    // XCD-bijective swizzle: 1536 blocks, chunk 192
    const int bid = blockIdx.x;
    const int wg  = (bid & 7) * 192 + (bid >> 3);
    const int e   = wg / 48;
    const int rem = wg % 48;
    const int ti  = rem % 12;
    const int tm  = rem / 12;

    const int tid  = threadIdx.x;
    const int lane = tid & 63;
    const int wave = tid >> 6;
    const int wr = wave >> 1;
    const int wc = wave & 1;

    const float* Ab = rin  + (size_t)e * NT * NH + (size_t)(tm * 128) * NH;
    const float* Gb = gate + (size_t)e * NI * NH + (size_t)(ti * 64) * NH;
    const float* Ub = up   + (size_t)e * NI * NH + (size_t)(ti * 64) * NH;

    const int a0_row = tid >> 2,            a0_cl = tid & 3;
    const int a1_row = (tid + 256) >> 2,    a1_cl = tid & 3;
    const int a0_c = a0_cl ^ (a0_row & 3);
    const int a1_c = a1_cl ^ (a1_row & 3);
    const int w_row = tid >> 2,             w_cl = tid & 3;
    const int w_c = w_cl ^ (w_row & 3);

    const float* A0src = Ab + (size_t)a0_row * NH + a0_c * 8;
    const float* A1src = Ab + (size_t)a1_row * NH + a1_c * 8;
    const float* Gsrc  = Gb + (size_t)w_row * NH + w_c * 8;
    const float* Usrc  = Ub + (size_t)w_row * NH + w_c * 8;

    floatx4 accg[4][2], accu[4][2];
    #pragma unroll
    for (int m = 0; m < 4; ++m)
        #pragma unroll
        for (int n = 0; n < 2; ++n) {
            accg[m][n] = (floatx4)0.f;
            accu[m][n] = (floatx4)0.f;
        }

    const int frow = lane & 15;
    const int h    = lane >> 4;
    const int KT = NH / 32;

    floatx4 P[4][2];

#define ISSUE(kt) do {                                                       \
        const int k_ = (kt) * 32;                                            \
        P[0][0] = *(const floatx4*)(A0src + k_);                             \
        P[0][1] = *(const floatx4*)(A0src + k_ + 4);                         \
        P[1][0] = *(const floatx4*)(A1src + k_);                             \
        P[1][1] = *(const floatx4*)(A1src + k_ + 4);                         \
        P[2][0] = *(const floatx4*)(Gsrc + k_);                              \
        P[2][1] = *(const floatx4*)(Gsrc + k_ + 4);                          \
        P[3][0] = *(const floatx4*)(Usrc + k_);                              \
        P[3][1] = *(const floatx4*)(Usrc + k_ + 4);                          \
    } while (0)

#define WRITE(b) do {                                                       \
        *(uintx4*)&SA[b][a0_row][a0_cl * 8] = pack8(P[0][0], P[0][1]);       \
        *(uintx4*)&SA[b][a1_row][a1_cl * 8] = pack8(P[1][0], P[1][1]);       \
        *(uintx4*)&SG[b][w_row][w_cl * 8]   = pack8(P[2][0], P[2][1]);       \
        *(uintx4*)&SU[b][w_row][w_cl * 8]   = pack8(P[3][0], P[3][1]);       \
    } while (0)

#define COMPUTE(b) do {                                                      \
        short8 af[4], gf[2], uf[2];                                          \
        _Pragma("unroll")                                                    \
        for (int m = 0; m < 4; ++m) {                                        \
            const int R = wr * 64 + m * 16 + frow;                           \
            const int p = h ^ (R & 3);                                       \
            af[m] = *(const short8*)&SA[b][R][p * 8];                        \
        }                                                                    \
        _Pragma("unroll")                                                    \
        for (int n = 0; n < 2; ++n) {                                        \
            const int R = wc * 32 + n * 16 + frow;                           \
            const int p = h ^ (R & 3);                                       \
            gf[n] = *(const short8*)&SG[b][R][p * 8];                        \
            uf[n] = *(const short8*)&SU[b][R][p * 8];                        \
        }                                                                    \
        _Pragma("unroll")                                                    \
        for (int m = 0; m < 4; ++m)                                          \
            _Pragma("unroll")                                                \
            for (int n = 0; n < 2; ++n) {                                    \
                accg[m][n] = __builtin_amdgcn_mfma_f32_16x16x32_bf16(        \
                    af[m], gf[n], accg[m][n], 0, 0, 0);                      \
                accu[m][n] = __builtin_amdgcn_mfma_f32_16x16x32_bf16(        \
                    af[m], uf[n], accu[m][n], 0, 0, 0);                      \
            }                                                                \
    } while (0)

#define ENDBAR() do {                                                        \
        asm volatile("s_waitcnt lgkmcnt(0)" ::: "memory");                   \
        __builtin_amdgcn_sched_barrier(0);                                   \
        __builtin_amdgcn_s_barrier();                                        \
    } while (0)

    ISSUE(0);
    WRITE(0);
    ISSUE(1);
    ENDBAR();

    for (int kt = 0; kt < KT; kt += 2) {
        COMPUTE(0);
        WRITE(1);
        if (kt + 2 < KT) ISSUE(kt + 2);
        ENDBAR();
        COMPUTE(1);
        if (kt + 2 < KT) WRITE(0);
        if (kt + 3 < KT) ISSUE(kt + 3);
        ENDBAR();
    }
#undef ISSUE
#undef WRITE
#undef COMPUTE
#undef ENDBAR

    const int ccol  = lane & 15;
    const int crow0 = (lane >> 4) * 4;
    const size_t hbase = ((size_t)e * NT + (size_t)tm * 128) * NI + ti * 64;
    #pragma unroll
    for (int m = 0; m < 4; ++m)
        #pragma unroll
        for (int n = 0; n < 2; ++n)
            #pragma unroll
            for (int j = 0; j < 4; ++j) {
                const float g = accg[m][n][j];
                const float u = accu[m][n][j];
                const float hh = (g / (1.f + __expf(-g))) * u;
                const int row = wr * 64 + m * 16 + crow0 + j;
                const int col = wc * 32 + n * 16 + ccol;
                hidden[hbase + (size_t)row * NI + col] = f2bf(hh);
            }
}

// ---------------------------------------------------------------------------
// Kernel 2: down projection, rebuilt on the R13 reg-staged structure.
// A = hidden [T,I] bf16 (loaded short8 direct), B = down [H,I] f32
// (converted to bf16 at stage time). BM=128(T) x BN=128(H), BK=32 over I.
// 4 waves (2x2), 4x4 frags -> acc 64 AGPR. LDS: SA+SB dbuf bf16 = 32 KB
// -> 3 blocks/CU. LDS traffic/iter: 48 KB (was 72 with f32 B).
// ---------------------------------------------------------------------------
__global__ __launch_bounds__(256, 3) void moe_down(
    const ushort* __restrict__ hidden, const float* __restrict__ down,
    float* __restrict__ out)
{
    __shared__ ushort SA[2][128][32];
    __shared__ ushort SB[2][128][32];

    // XCD-bijective swizzle: 2048 blocks, chunk 256
    const int bid = blockIdx.x;
    const int wg  = (bid & 7) * 256 + (bid >> 3);
    const int e   = wg >> 6;
    const int rem = wg & 63;
    const int tn  = rem & 15;   // H tile of 128
    const int tm  = rem >> 4;   // T tile of 128

    const int tid  = threadIdx.x;
    const int lane = tid & 63;
    const int wave = tid >> 6;
    const int wr = wave >> 1, wc = wave & 1;

    const ushort* Ab = hidden + ((size_t)e * NT + (size_t)tm * 128) * NI;
    const float*  Bb = down + (size_t)e * NH * NI + (size_t)(tn * 128) * NI;

    // staging geometry (R13 pattern): s_row = tid>>2 in [0,64), phys chunk
    // tid&3 (LINEAR write), slot1 = row+64 ((row+64)&3 == row&3 -> same c).
    const int s_row = tid >> 2;
    const int s_cl  = tid & 3;
    const int s_c   = s_cl ^ (s_row & 3);
    const ushort* A0src = Ab + (size_t)s_row * NI + s_c * 8;
    const ushort* A1src = Ab + (size_t)(s_row + 64) * NI + s_c * 8;
    const float*  B0src = Bb + (size_t)s_row * NI + s_c * 8;
    const float*  B1src = Bb + (size_t)(s_row + 64) * NI + s_c * 8;

    floatx4 acc[4][4];
    #pragma unroll
    for (int m = 0; m < 4; ++m)
        #pragma unroll
        for (int n = 0; n < 4; ++n) acc[m][n] = (floatx4)0.f;

    const int frow = lane & 15;
    const int h    = lane >> 4;
    const int KT = NI / 32;   // 24 (even)

    short8  Pa[2];
    floatx4 Pb[2][2];

#define ISSUE(kt) do {                                                       \
        const int k_ = (kt) * 32;                                            \
        Pa[0]    = *(const short8*)(A0src + k_);                             \
        Pa[1]    = *(const short8*)(A1src + k_);                             \
        Pb[0][0] = *(const floatx4*)(B0src + k_);                            \
        Pb[0][1] = *(const floatx4*)(B0src + k_ + 4);                        \
        Pb[1][0] = *(const floatx4*)(B1src + k_);                            \
        Pb[1][1] = *(const floatx4*)(B1src + k_ + 4);                        \
    } while (0)

#define WRITE(b) do {                                                        \
        *(short8*)&SA[b][s_row][s_cl * 8]      = Pa[0];                      \
        *(short8*)&SA[b][s_row + 64][s_cl * 8] = Pa[1];                      \
        *(uintx4*)&SB[b][s_row][s_cl * 8]      = pack8(Pb[0][0], Pb[0][1]);  \
        *(uintx4*)&SB[b][s_row + 64][s_cl * 8] = pack8(Pb[1][0], Pb[1][1]);  \
    } while (0)

#define COMPUTE(b) do {                                                      \
        short8 af[4], bf[4];                                                 \
        _Pragma("unroll")                                                    \
        for (int m = 0; m < 4; ++m) {                                        \
            const int R = wr * 64 + m * 16 + frow;                           \
            const int p = h ^ (R & 3);                                       \
            af[m] = *(const short8*)&SA[b][R][p * 8];                        \
        }                                                                    \
        _Pragma("unroll")                                                    \
        for (int n = 0; n < 4; ++n) {                                        \
            const int R = wc * 64 + n * 16 + frow;                           \
            const int p = h ^ (R & 3);                                       \
            bf[n] = *(const short8*)&SB[b][R][p * 8];                        \
        }                                                                    \
        _Pragma("unroll")                                                    \
        for (int m = 0; m < 4; ++m)                                          \
            _Pragma("unroll")                                                \
            for (int n = 0; n < 4; ++n)                                      \
                acc[m][n] = __builtin_amdgcn_mfma_f32_16x16x32_bf16(         \
                    af[m], bf[n], acc[m][n], 0, 0, 0);                       \
    } while (0)

#define ENDBAR() do {                                                        \
        asm volatile("s_waitcnt lgkmcnt(0)" ::: "memory");                   \
        __builtin_amdgcn_sched_barrier(0);                                   \
        __builtin_amdgcn_s_barrier();                                        \
    } while (0)

    ISSUE(0);
    WRITE(0);
    ISSUE(1);
    ENDBAR();

    for (int kt = 0; kt < KT; kt += 2) {
        COMPUTE(0);
        WRITE(1);
        if (kt + 2 < KT) ISSUE(kt + 2);
        ENDBAR();
        COMPUTE(1);
        if (kt + 2 < KT) WRITE(0);
        if (kt + 3 < KT) ISSUE(kt + 3);
        ENDBAR();
    }
#undef ISSUE
#undef WRITE
#undef COMPUTE
#undef ENDBAR

    const int ccol  = lane & 15;
    const int crow0 = (lane >> 4) * 4;
    float* Ob = out + ((size_t)e * NT + (size_t)tm * 128) * NH + tn * 128;
    #pragma unroll
    for (int m = 0; m < 4; ++m)
        #pragma unroll
        for (int n = 0; n < 4; ++n)
            #pragma unroll
            for (int j = 0; j < 4; ++j) {
                const int row = wr * 64 + m * 16 + crow0 + j;
                const int col = wc * 64 + n * 16 + ccol;
                Ob[(size_t)row * NH + col] = acc[m][n][j];
            }
}

extern "C" void kernel_launch(void* const* d_in, const int* in_sizes, int n_in,
                              void* d_out, int out_size, void* d_ws, size_t ws_size,
                              hipStream_t stream) {
    const float* rin  = (const float*)d_in[0];
    const float* gate = (const float*)d_in[1];
    const float* up   = (const float*)d_in[2];
    const float* down = (const float*)d_in[3];
    float* out = (float*)d_out;
    ushort* hidden = (ushort*)d_ws;   // [E,T,I] bf16, 24 MB

    moe_gateup<<<dim3(1536), dim3(256), 0, stream>>>(rin, gate, up, hidden);
    moe_down<<<dim3(2048), dim3(256), 0, stream>>>(hidden, down, out);
}